// Round 5
// baseline (2392.882 us; speedup 1.0000x reference)
//
#include <hip/hip_runtime.h>

#define TT 2048
#define BB 256
#define II 64
#define HH 128
#define CH 64   // x-chunk depth (steps staged in LDS per global-load burst)

typedef __fp16 f16;
typedef __fp16 h2  __attribute__((ext_vector_type(2)));
typedef __fp16 v8h __attribute__((ext_vector_type(8)));
typedef float  v4f __attribute__((ext_vector_type(4)));

union HI { int i; h2 h; };
__device__ __forceinline__ h2  i2h(int v) { HI u; u.i = v; return u.h; }
__device__ __forceinline__ int h2i(h2 v)  { HI u; u.h = v; return u.i; }

__device__ __forceinline__ float fsig(float x) {
  return __builtin_amdgcn_rcpf(1.0f + __expf(-x));
}
__device__ __forceinline__ float ftanh(float x) {
  return 1.0f - 2.0f * __builtin_amdgcn_rcpf(1.0f + __expf(2.0f * x));
}

// One block per batch row, 256 threads = 4 waves (1/SIMD).
// A-operand M=16 tile, only row 0 real = [h(128) | x(64)]; lanes with
// (lane&15)!=0 keep zero A-frags in registers (never touch LDS).
// Wave w owns output cols [32w,32w+32); B-frags register-resident.
// NO global load/store inside a steady-state step: x staged in 64-step LDS
// chunks, outputs buffered in LDS and flushed once per chunk — so the
// compiler's vmcnt(0)-before-s_barrier drain hits ~1x per 64 steps, not 1x/step.
__global__ __launch_bounds__(256, 1) void gru_mfma(
    const float* __restrict__ x,
    const float* __restrict__ Wir, const float* __restrict__ Wiz, const float* __restrict__ Win,
    const float* __restrict__ bir, const float* __restrict__ biz, const float* __restrict__ bin_,
    const float* __restrict__ Whr, const float* __restrict__ Whz, const float* __restrict__ Whn,
    const float* __restrict__ bhn, const float* __restrict__ Wc,  const float* __restrict__ bc,
    float* __restrict__ out)
{
  const int t = threadIdx.x, b = blockIdx.x;
  const int w = t >> 6;     // wave id
  const int l = t & 63;     // lane
  const int q = l >> 4;     // quad
  const int r = l & 15;

  __shared__ f16  hbuf[2][HH];      // h state, double-buffered (512 B)
  __shared__ f16  xch[CH][72];      // x chunk, row stride 72 (pad: bank spread)
  __shared__ float obuf[2][CH];     // output ring, double-buffered

  // ---- resident B fragments: B[k=32kt+8q+j][n=32w+16ct+r] (R4-verified) ----
  v8h br_[6][2], bz_[6][2], bnh_[4][2], bnx_[2][2];
  for (int kt = 0; kt < 6; ++kt)
    for (int ct = 0; ct < 2; ++ct) {
      const int n = 32 * w + 16 * ct + r;
      v8h vr, vz;
      for (int j = 0; j < 8; ++j) {
        const int kg = 32 * kt + 8 * q + j;
        vr[j] = (f16)((kg < HH) ? Whr[kg * HH + n] : Wir[(kg - HH) * HH + n]);
        vz[j] = (f16)((kg < HH) ? Whz[kg * HH + n] : Wiz[(kg - HH) * HH + n]);
      }
      br_[kt][ct] = vr; bz_[kt][ct] = vz;
    }
  for (int kt = 0; kt < 4; ++kt)
    for (int ct = 0; ct < 2; ++ct) {
      const int n = 32 * w + 16 * ct + r;
      v8h v;
      for (int j = 0; j < 8; ++j) v[j] = (f16)Whn[(32 * kt + 8 * q + j) * HH + n];
      bnh_[kt][ct] = v;
    }
  for (int kt = 0; kt < 2; ++kt)
    for (int ct = 0; ct < 2; ++ct) {
      const int n = 32 * w + 16 * ct + r;
      v8h v;
      for (int j = 0; j < 8; ++j) v[j] = (f16)Win[(32 * kt + 8 * q + j) * HH + n];
      bnx_[kt][ct] = v;
    }

  float birc[2], bizc[2], binc[2], bhnc[2], hst[2] = {0.f, 0.f};
  for (int ct = 0; ct < 2; ++ct) {
    const int n = 32 * w + 16 * ct + r;
    birc[ct] = bir[n]; bizc[ct] = biz[n]; binc[ct] = bin_[n]; bhnc[ct] = bhn[n];
  }
  const float bc0 = bc[0];

  h2 wcp[4];
  if (w == 2 && q == 1) {
    for (int p = 0; p < 4; ++p)
      wcp[p] = __builtin_amdgcn_cvt_pkrtz(Wc[8 * r + 2 * p], Wc[8 * r + 2 * p + 1]);
  }

  if (t < HH) { hbuf[0][t] = (f16)0.f; hbuf[1][t] = (f16)0.f; }
  // (visibility of hbuf zero is covered by the s=0 chunk-load barrier)

  // A-frags persist across iterations; non-(r==0) lanes stay zero forever.
  v8h af[6] = {};

  #pragma unroll 1
  for (int s = 0; s < TT; ++s) {
    const int cur = s & 1, nxt = cur ^ 1;

    if ((s & (CH - 1)) == 0) {
      // stage x[s .. s+CH) : 256 threads x 16 contiguous floats each
      const int sl = t >> 2, c0 = (t & 3) * 16;
      const float4* xp = (const float4*)(x + ((size_t)(s + sl) * BB + b) * II + c0);
      float4 a0 = xp[0], a1 = xp[1], a2 = xp[2], a3 = xp[3];
      int4 p0, p1;
      p0.x = h2i(__builtin_amdgcn_cvt_pkrtz(a0.x, a0.y));
      p0.y = h2i(__builtin_amdgcn_cvt_pkrtz(a0.z, a0.w));
      p0.z = h2i(__builtin_amdgcn_cvt_pkrtz(a1.x, a1.y));
      p0.w = h2i(__builtin_amdgcn_cvt_pkrtz(a1.z, a1.w));
      p1.x = h2i(__builtin_amdgcn_cvt_pkrtz(a2.x, a2.y));
      p1.y = h2i(__builtin_amdgcn_cvt_pkrtz(a2.z, a2.w));
      p1.z = h2i(__builtin_amdgcn_cvt_pkrtz(a3.x, a3.y));
      p1.w = h2i(__builtin_amdgcn_cvt_pkrtz(a3.z, a3.w));
      *(int4*)&xch[sl][c0]     = p0;
      *(int4*)&xch[sl][c0 + 8] = p1;
      __syncthreads();
    }

    // flush previous chunk's outputs (wave 1), once per chunk
    if ((s & (CH - 1)) == 1 && s > CH && w == 1) {
      const int base = s - 1 - CH;
      out[(size_t)(base + l) * BB + b] = obuf[(((s - 1) >> 6) & 1) ^ 1][l];
    }

    // classifier for step s-1 from hbuf[cur] (wave 2, quad 1)
    if (w == 2 && q == 1 && s > 0) {
      const int4 hv = *(const int4*)&hbuf[cur][8 * r];
      float c = 0.f;
      c = __builtin_amdgcn_fdot2(i2h(hv.x), wcp[0], c, false);
      c = __builtin_amdgcn_fdot2(i2h(hv.y), wcp[1], c, false);
      c = __builtin_amdgcn_fdot2(i2h(hv.z), wcp[2], c, false);
      c = __builtin_amdgcn_fdot2(i2h(hv.w), wcp[3], c, false);
      c += __shfl_xor(c, 1, 64);
      c += __shfl_xor(c, 2, 64);
      c += __shfl_xor(c, 4, 64);
      c += __shfl_xor(c, 8, 64);
      const int idx = s - 1;
      if (r == 0) obuf[(idx >> 6) & 1][idx & (CH - 1)] = fsig(c + bc0);
    }

    // A-fragments (row 0 only): A[m=r][k=32kt+8q+j]
    if (r == 0) {
      const int sc = s & (CH - 1);
      af[0] = *(const v8h*)&hbuf[cur][8 * q];
      af[1] = *(const v8h*)&hbuf[cur][32 + 8 * q];
      af[2] = *(const v8h*)&hbuf[cur][64 + 8 * q];
      af[3] = *(const v8h*)&hbuf[cur][96 + 8 * q];
      af[4] = *(const v8h*)&xch[sc][8 * q];
      af[5] = *(const v8h*)&xch[sc][32 + 8 * q];
    }

    v4f ar[2], az[2], anh[2], anx[2];
    #pragma unroll
    for (int ct = 0; ct < 2; ++ct) {
      v4f a = {0.f, 0.f, 0.f, 0.f};
      #pragma unroll
      for (int kt = 0; kt < 6; ++kt)
        a = __builtin_amdgcn_mfma_f32_16x16x32_f16(af[kt], br_[kt][ct], a, 0, 0, 0);
      ar[ct] = a;
      a = (v4f){0.f, 0.f, 0.f, 0.f};
      #pragma unroll
      for (int kt = 0; kt < 6; ++kt)
        a = __builtin_amdgcn_mfma_f32_16x16x32_f16(af[kt], bz_[kt][ct], a, 0, 0, 0);
      az[ct] = a;
      a = (v4f){0.f, 0.f, 0.f, 0.f};
      #pragma unroll
      for (int kt = 0; kt < 4; ++kt)
        a = __builtin_amdgcn_mfma_f32_16x16x32_f16(af[kt], bnh_[kt][ct], a, 0, 0, 0);
      anh[ct] = a;
      a = (v4f){0.f, 0.f, 0.f, 0.f};
      #pragma unroll
      for (int kt = 0; kt < 2; ++kt)
        a = __builtin_amdgcn_mfma_f32_16x16x32_f16(af[4 + kt], bnx_[kt][ct], a, 0, 0, 0);
      anx[ct] = a;
    }

    // epilogue: C row 0 = reg 0 of quad-0 lanes; col = 32w+16ct+r
    if (q == 0) {
      #pragma unroll
      for (int ct = 0; ct < 2; ++ct) {
        float rr = fsig(ar[ct][0] + birc[ct]);
        float zz = fsig(az[ct][0] + bizc[ct]);
        float nn = ftanh(anx[ct][0] + binc[ct] + rr * (anh[ct][0] + bhnc[ct]));
        hst[ct] = (1.f - zz) * nn + zz * hst[ct];
        hbuf[nxt][32 * w + 16 * ct + r] = (f16)hst[ct];
      }
    }
    __syncthreads();
  }

  // tail: flush outputs [TT-CH, TT-1) from obuf, then out[TT-1] from h_final
  if (w == 1 && l < CH - 1) out[(size_t)(TT - CH + l) * BB + b] = obuf[1][l];
  if (w == 2 && q == 1) {
    const int4 hv = *(const int4*)&hbuf[0][8 * r];
    float c = 0.f;
    c = __builtin_amdgcn_fdot2(i2h(hv.x), wcp[0], c, false);
    c = __builtin_amdgcn_fdot2(i2h(hv.y), wcp[1], c, false);
    c = __builtin_amdgcn_fdot2(i2h(hv.z), wcp[2], c, false);
    c = __builtin_amdgcn_fdot2(i2h(hv.w), wcp[3], c, false);
    c += __shfl_xor(c, 1, 64);
    c += __shfl_xor(c, 2, 64);
    c += __shfl_xor(c, 4, 64);
    c += __shfl_xor(c, 8, 64);
    if (r == 0) out[(size_t)(TT - 1) * BB + b] = fsig(c + bc0);
  }
}

extern "C" void kernel_launch(void* const* d_in, const int* in_sizes, int n_in,
                              void* d_out, int out_size, void* d_ws, size_t ws_size,
                              hipStream_t stream) {
  const float* x    = (const float*)d_in[0];
  const float* Wir  = (const float*)d_in[1];
  const float* Wiz  = (const float*)d_in[2];
  const float* Win  = (const float*)d_in[3];
  const float* bir  = (const float*)d_in[4];
  const float* biz  = (const float*)d_in[5];
  const float* bin_ = (const float*)d_in[6];
  const float* Whr  = (const float*)d_in[7];
  const float* Whz  = (const float*)d_in[8];
  const float* Whn  = (const float*)d_in[9];
  const float* bhn  = (const float*)d_in[10];
  const float* Wc   = (const float*)d_in[11];
  const float* bc   = (const float*)d_in[12];
  float* out = (float*)d_out;

  gru_mfma<<<dim3(BB), dim3(256), 0, stream>>>(
      x, Wir, Wiz, Win, bir, biz, bin_, Whr, Whz, Whn, bhn, Wc, bc, out);
}

// Round 6
// 1989.167 us; speedup vs baseline: 1.2030x; 1.2030x over previous
//
#include <hip/hip_runtime.h>

#define TT 2048
#define BB 256
#define II 64
#define HH 128
#define CH 64   // x-chunk depth

typedef __fp16 f16;
typedef __fp16 h2  __attribute__((ext_vector_type(2)));
typedef __fp16 v8h __attribute__((ext_vector_type(8)));
typedef float  v4f __attribute__((ext_vector_type(4)));

union HI { int i; h2 h; };
__device__ __forceinline__ h2  i2h(int v) { HI u; u.i = v; return u.h; }
__device__ __forceinline__ int h2i(h2 v)  { HI u; u.h = v; return u.i; }

__device__ __forceinline__ float fsig(float x) {
  return __builtin_amdgcn_rcpf(1.0f + __expf(-x));
}
__device__ __forceinline__ float ftanh(float x) {
  return 1.0f - 2.0f * __builtin_amdgcn_rcpf(1.0f + __expf(2.0f * x));
}

// Raw barrier: LDS-drain only. Does NOT drain vmcnt -> global loads/stores
// stay in flight across step barriers (unlike __syncthreads).
__device__ __forceinline__ void bar_lgkm() {
  asm volatile("s_waitcnt lgkmcnt(0)\n\ts_barrier" ::: "memory");
}

// One block per batch row, 256 threads = 4 waves (1/SIMD).
// A-operand M=16 tile, row 0 real = [h(128) | x(64)]; only r==0 lanes read LDS,
// other lanes keep zero A-frags. Wave w owns output cols [32w,32w+32).
// Steady-state step: 4 barrier-dependent ds_reads + 36 MFMA (depth-3 chains) +
// epilogue; ONE lgkm-only barrier. x double-buffered in REGISTERS across
// 64-step chunks (loads in flight 64 steps). Classifier: epilogue writes 64
// fp32 partials; wave 3 reduces previous step's partials (overlaps MFMAs),
// one fire-and-forget global store per step.
__global__ __launch_bounds__(256, 1) void gru_mfma(
    const float* __restrict__ x,
    const float* __restrict__ Wir, const float* __restrict__ Wiz, const float* __restrict__ Win,
    const float* __restrict__ bir, const float* __restrict__ biz, const float* __restrict__ bin_,
    const float* __restrict__ Whr, const float* __restrict__ Whz, const float* __restrict__ Whn,
    const float* __restrict__ bhn, const float* __restrict__ Wc,  const float* __restrict__ bc,
    float* __restrict__ out)
{
  const int t = threadIdx.x, b = blockIdx.x;
  const int w = t >> 6;     // wave id
  const int l = t & 63;     // lane
  const int q = l >> 4;     // quad
  const int r = l & 15;

  __shared__ f16  hbuf[2][HH];     // h state, double-buffered
  __shared__ f16  xch[CH][72];     // x chunk (stride 72 f16 = 144 B, 16B-aligned)
  __shared__ float cpart[2][64];   // classifier partials, double-buffered

  // ---- resident B fragments: B[k=32kt+8q+j][n=32w+16ct+r] (R4-verified) ----
  v8h br_[6][2], bz_[6][2], bnh_[4][2], bnx_[2][2];
  for (int kt = 0; kt < 6; ++kt)
    for (int ct = 0; ct < 2; ++ct) {
      const int n = 32 * w + 16 * ct + r;
      v8h vr, vz;
      for (int j = 0; j < 8; ++j) {
        const int kg = 32 * kt + 8 * q + j;
        vr[j] = (f16)((kg < HH) ? Whr[kg * HH + n] : Wir[(kg - HH) * HH + n]);
        vz[j] = (f16)((kg < HH) ? Whz[kg * HH + n] : Wiz[(kg - HH) * HH + n]);
      }
      br_[kt][ct] = vr; bz_[kt][ct] = vz;
    }
  for (int kt = 0; kt < 4; ++kt)
    for (int ct = 0; ct < 2; ++ct) {
      const int n = 32 * w + 16 * ct + r;
      v8h v;
      for (int j = 0; j < 8; ++j) v[j] = (f16)Whn[(32 * kt + 8 * q + j) * HH + n];
      bnh_[kt][ct] = v;
    }
  for (int kt = 0; kt < 2; ++kt)
    for (int ct = 0; ct < 2; ++ct) {
      const int n = 32 * w + 16 * ct + r;
      v8h v;
      for (int j = 0; j < 8; ++j) v[j] = (f16)Win[(32 * kt + 8 * q + j) * HH + n];
      bnx_[kt][ct] = v;
    }

  float birc[2], bizc[2], binc[2], bhnc[2], hst[2] = {0.f, 0.f};
  for (int ct = 0; ct < 2; ++ct) {
    const int n = 32 * w + 16 * ct + r;
    birc[ct] = bir[n]; bizc[ct] = biz[n]; binc[ct] = bin_[n]; bhnc[ct] = bhn[n];
  }
  const float bc0 = bc[0];
  const float wcA = Wc[32 * w + r], wcB = Wc[32 * w + 16 + r];

  // ---- x chunk 0 -> registers (double-buffer seed) ----
  const int sl = t >> 2, c0 = (t & 3) * 16;   // thread covers x[s+sl][c0..c0+16)
  float4 xr0, xr1, xr2, xr3;
  {
    const float4* xp = (const float4*)(x + ((size_t)sl * BB + b) * II + c0);
    xr0 = xp[0]; xr1 = xp[1]; xr2 = xp[2]; xr3 = xp[3];
  }

  if (t < HH) { hbuf[0][t] = (f16)0.f; hbuf[1][t] = (f16)0.f; }
  __syncthreads();   // one full barrier in prologue (drains weight loads etc.)

  v8h af[6] = {};    // non-(r==0) lanes stay zero forever

  #pragma unroll 1
  for (int s = 0; s < TT; ++s) {
    const int cur = s & 1, nxt = cur ^ 1, sc = s & (CH - 1);

    if (sc == 0) {
      // stage chunk (from regs loaded 64 steps ago) into LDS
      int4 p0, p1;
      p0.x = h2i(__builtin_amdgcn_cvt_pkrtz(xr0.x, xr0.y));
      p0.y = h2i(__builtin_amdgcn_cvt_pkrtz(xr0.z, xr0.w));
      p0.z = h2i(__builtin_amdgcn_cvt_pkrtz(xr1.x, xr1.y));
      p0.w = h2i(__builtin_amdgcn_cvt_pkrtz(xr1.z, xr1.w));
      p1.x = h2i(__builtin_amdgcn_cvt_pkrtz(xr2.x, xr2.y));
      p1.y = h2i(__builtin_amdgcn_cvt_pkrtz(xr2.z, xr2.w));
      p1.z = h2i(__builtin_amdgcn_cvt_pkrtz(xr3.x, xr3.y));
      p1.w = h2i(__builtin_amdgcn_cvt_pkrtz(xr3.z, xr3.w));
      *(int4*)&xch[sl][c0]     = p0;
      *(int4*)&xch[sl][c0 + 8] = p1;
      // issue next chunk's loads; first use is 64 steps away
      const int nb = s + CH;
      if (nb < TT) {
        const float4* xp = (const float4*)(x + ((size_t)(nb + sl) * BB + b) * II + c0);
        xr0 = xp[0]; xr1 = xp[1]; xr2 = xp[2]; xr3 = xp[3];
      }
      bar_lgkm();                       // xch visible; x-loads stay in flight
      if (r == 0) {
        af[4] = *(const v8h*)&xch[0][8 * q];
        af[5] = *(const v8h*)&xch[0][32 + 8 * q];
      }
    }

    // wave 3: pick up previous step's classifier partials (1 ds_read_b32)
    float cred = 0.f;
    if (w == 3 && s > 0) cred = cpart[nxt][l];

    // h A-frags (barrier-dependent; 4 reads)
    if (r == 0) {
      af[0] = *(const v8h*)&hbuf[cur][8 * q];
      af[1] = *(const v8h*)&hbuf[cur][32 + 8 * q];
      af[2] = *(const v8h*)&hbuf[cur][64 + 8 * q];
      af[3] = *(const v8h*)&hbuf[cur][96 + 8 * q];
    }

    // MFMA phase: depth-3 chains (2 accumulators per gate) + scalar combine
    float arS[2], azS[2], anhS[2], anxS[2];
    #pragma unroll
    for (int ct = 0; ct < 2; ++ct) {
      v4f a0 = {0,0,0,0}, a1 = {0,0,0,0};
      v4f z0 = {0,0,0,0}, z1 = {0,0,0,0};
      v4f n0 = {0,0,0,0}, n1 = {0,0,0,0};
      v4f xx = {0,0,0,0};
      a0 = __builtin_amdgcn_mfma_f32_16x16x32_f16(af[0], br_[0][ct], a0, 0, 0, 0);
      z0 = __builtin_amdgcn_mfma_f32_16x16x32_f16(af[0], bz_[0][ct], z0, 0, 0, 0);
      n0 = __builtin_amdgcn_mfma_f32_16x16x32_f16(af[0], bnh_[0][ct], n0, 0, 0, 0);
      xx = __builtin_amdgcn_mfma_f32_16x16x32_f16(af[4], bnx_[0][ct], xx, 0, 0, 0);
      a1 = __builtin_amdgcn_mfma_f32_16x16x32_f16(af[3], br_[3][ct], a1, 0, 0, 0);
      z1 = __builtin_amdgcn_mfma_f32_16x16x32_f16(af[3], bz_[3][ct], z1, 0, 0, 0);
      n1 = __builtin_amdgcn_mfma_f32_16x16x32_f16(af[2], bnh_[2][ct], n1, 0, 0, 0);
      a0 = __builtin_amdgcn_mfma_f32_16x16x32_f16(af[1], br_[1][ct], a0, 0, 0, 0);
      z0 = __builtin_amdgcn_mfma_f32_16x16x32_f16(af[1], bz_[1][ct], z0, 0, 0, 0);
      n0 = __builtin_amdgcn_mfma_f32_16x16x32_f16(af[1], bnh_[1][ct], n0, 0, 0, 0);
      xx = __builtin_amdgcn_mfma_f32_16x16x32_f16(af[5], bnx_[1][ct], xx, 0, 0, 0);
      a1 = __builtin_amdgcn_mfma_f32_16x16x32_f16(af[4], br_[4][ct], a1, 0, 0, 0);
      z1 = __builtin_amdgcn_mfma_f32_16x16x32_f16(af[4], bz_[4][ct], z1, 0, 0, 0);
      n1 = __builtin_amdgcn_mfma_f32_16x16x32_f16(af[3], bnh_[3][ct], n1, 0, 0, 0);
      a0 = __builtin_amdgcn_mfma_f32_16x16x32_f16(af[2], br_[2][ct], a0, 0, 0, 0);
      z0 = __builtin_amdgcn_mfma_f32_16x16x32_f16(af[2], bz_[2][ct], z0, 0, 0, 0);
      a1 = __builtin_amdgcn_mfma_f32_16x16x32_f16(af[5], br_[5][ct], a1, 0, 0, 0);
      z1 = __builtin_amdgcn_mfma_f32_16x16x32_f16(af[5], bz_[5][ct], z1, 0, 0, 0);
      arS[ct]  = a0[0] + a1[0];
      azS[ct]  = z0[0] + z1[0];
      anhS[ct] = n0[0] + n1[0];
      anxS[ct] = xx[0];
    }

    // prefetch next step's x A-frags (latency hidden behind epilogue)
    if (r == 0 && sc != CH - 1) {
      af[4] = *(const v8h*)&xch[sc + 1][8 * q];
      af[5] = *(const v8h*)&xch[sc + 1][32 + 8 * q];
    }

    // epilogue: C row 0 = elem 0 of quad-0 lanes; col = 32w+16ct+r
    if (q == 0) {
      #pragma unroll
      for (int ct = 0; ct < 2; ++ct) {
        float rr = fsig(arS[ct] + birc[ct]);
        float zz = fsig(azS[ct] + bizc[ct]);
        float nn = ftanh(anxS[ct] + binc[ct] + rr * (anhS[ct] + bhnc[ct]));
        hst[ct] = (1.f - zz) * nn + zz * hst[ct];
        hbuf[nxt][32 * w + 16 * ct + r] = (f16)hst[ct];
      }
      cpart[cur][16 * w + r] = hst[0] * wcA + hst[1] * wcB;
    }

    // wave 3: finish previous step's classifier (shuffles overlap MFMAs above)
    if (w == 3 && s > 0) {
      cred += __shfl_xor(cred, 1, 64);
      cred += __shfl_xor(cred, 2, 64);
      cred += __shfl_xor(cred, 4, 64);
      cred += __shfl_xor(cred, 8, 64);
      cred += __shfl_xor(cred, 16, 64);
      cred += __shfl_xor(cred, 32, 64);
      if (l == 0) out[(size_t)(s - 1) * BB + b] = fsig(cred + bc0);  // in-flight OK
    }

    bar_lgkm();
  }

  // tail: out[TT-1] from cpart[(TT-1)&1] (= [1])
  if (w == 3) {
    float cred = cpart[1][l];
    cred += __shfl_xor(cred, 1, 64);
    cred += __shfl_xor(cred, 2, 64);
    cred += __shfl_xor(cred, 4, 64);
    cred += __shfl_xor(cred, 8, 64);
    cred += __shfl_xor(cred, 16, 64);
    cred += __shfl_xor(cred, 32, 64);
    if (l == 0) out[(size_t)(TT - 1) * BB + b] = fsig(cred + bc0);
  }
}

extern "C" void kernel_launch(void* const* d_in, const int* in_sizes, int n_in,
                              void* d_out, int out_size, void* d_ws, size_t ws_size,
                              hipStream_t stream) {
  const float* x    = (const float*)d_in[0];
  const float* Wir  = (const float*)d_in[1];
  const float* Wiz  = (const float*)d_in[2];
  const float* Win  = (const float*)d_in[3];
  const float* bir  = (const float*)d_in[4];
  const float* biz  = (const float*)d_in[5];
  const float* bin_ = (const float*)d_in[6];
  const float* Whr  = (const float*)d_in[7];
  const float* Whz  = (const float*)d_in[8];
  const float* Whn  = (const float*)d_in[9];
  const float* bhn  = (const float*)d_in[10];
  const float* Wc   = (const float*)d_in[11];
  const float* bc   = (const float*)d_in[12];
  float* out = (float*)d_out;

  gru_mfma<<<dim3(BB), dim3(256), 0, stream>>>(
      x, Wir, Wiz, Win, bir, biz, bin_, Whr, Whz, Whn, bhn, Wc, bc, out);
}